// Round 5
// baseline (518.742 us; speedup 1.0000x reference)
//
#include <hip/hip_runtime.h>

// ---------------------------------------------------------------------------
// StandAttention: out = softmax_causal((xWq+bq)(xWk+bk)^T / sqrt(d)) (xWv+bv) Wo + bo
// b=4, s=4096, d=1024. fp32 in/out, bf16 MFMA compute.
//
// R11 changes vs R10 (R10: 517 us. Re-derivation: MfmaUtil ~= % of 2.5PF on
// busy CUs; all R6-R10 variants run ~880 TF/CU = the m97-family ceiling.
// Shared invariant: 16 MFMA per barrier. PV is worst (522 TF, only 16 MFMA
// per barrier-PAIR). Lever: BK=64 -> 2x MFMA per barrier-pair):
//  - gemm256q: 256^2 tile, BK=64, ring-2 dbuf (128KiB), 64 MFMA per
//    barrier-pair, balanced 8/4/8/4 ds_read pattern (A-half x k interleave,
//    <=12 live frags), chunk^(row&7) swizzle, counted vmcnt(8) ring.
//  - gemm_pv64: PV at BK=64, 32 MFMA per barrier-pair, 66 K-tiles/block
//    (paired (j,31-j)), 96KiB LDS, vmcnt(6) ring.
//  - SGB interleave dropped (R9: null). Raw barriers + SPIN fences kept.
// ---------------------------------------------------------------------------

typedef unsigned short u16;
typedef __attribute__((ext_vector_type(4))) unsigned short u16x4;
typedef __attribute__((ext_vector_type(8))) unsigned short u16x8;
typedef __attribute__((ext_vector_type(8))) __bf16 bf16x8;
typedef __attribute__((ext_vector_type(4))) float f32x4;

typedef const __attribute__((address_space(1))) void* as1cp;
typedef __attribute__((address_space(3))) void* as3p;

#define SBAR() __builtin_amdgcn_s_barrier()
#define SPIN() __builtin_amdgcn_sched_barrier(0)

struct GemmPtrs {
  const u16* A[4];
  const u16* B[4];
  const float* bias[4];
  void* C[4];
};
struct TransPtrs {
  const void* in[4];
  u16* out[4];
};
struct SmPtrs {
  u16* P[4];
};

__device__ __forceinline__ u16 f2bf(float f) {
  union { float f; unsigned int i; } c; c.f = f;
  unsigned int r = c.i + 0x7fffu + ((c.i >> 16) & 1u);   // RNE
  return (u16)(r >> 16);
}
__device__ __forceinline__ float bf2f(u16 u) {
  union { unsigned int i; float f; } c; c.i = ((unsigned int)u) << 16;
  return c.f;
}

// ---------------- cast fp32 -> bf16 (vectorized) ----------------
__global__ __launch_bounds__(256) void cast_f32_bf16(const float* __restrict__ in,
                                                     u16* __restrict__ out, int n4) {
  int i = blockIdx.x * blockDim.x + threadIdx.x;
  if (i >= n4) return;
  float4 v = ((const float4*)in)[i];
  u16x4 u;
  u.x = f2bf(v.x); u.y = f2bf(v.y); u.z = f2bf(v.z); u.w = f2bf(v.w);
  ((u16x4*)out)[i] = u;
}

// ---------------- LDS-tiled transpose (-> bf16), batched by z ----------------
template <bool IN_F32>
__global__ __launch_bounds__(256) void transpose_to_bf16(TransPtrs tp, int R, int C) {
  __shared__ u16 t[32][34];
  int z = blockIdx.z;
  int tx = threadIdx.x, ty = threadIdx.y;
  int c0 = blockIdx.x * 32, r0 = blockIdx.y * 32;
#pragma unroll
  for (int dy = 0; dy < 4; ++dy) {
    int r = r0 + ty + dy * 8;
    int c = c0 + tx;
    u16 hv;
    if (IN_F32) hv = f2bf(((const float*)tp.in[z])[(size_t)r * C + c]);
    else        hv = ((const u16*)tp.in[z])[(size_t)r * C + c];
    t[ty + dy * 8][tx] = hv;
  }
  __syncthreads();
  u16* op = tp.out[z];
#pragma unroll
  for (int dy = 0; dy < 4; ++dy) {
    int a = ty + dy * 8;
    op[(size_t)(c0 + a) * R + r0 + tx] = t[tx][a];
  }
}

// ---------------- causal softmax, in-place, trimmed to j<=row ----------------
__global__ __launch_bounds__(256) void softmax_causal(SmPtrs sp) {
  int row = blockIdx.x;
  u16* P = sp.P[blockIdx.y];
  int tid = threadIdx.x;
  int lane = tid & 63, wv = tid >> 6;
  u16x8* prow = (u16x8*)(P + (size_t)row * 4096);
  int nch = (row >> 3) + 1;           // vec8 chunks containing any j<=row
  int fend = ((row >> 7) + 1) << 4;   // chunks to the 128 boundary PV reads
  int c0 = tid, c1 = tid + 256;
  bool a0 = c0 < nch, a1 = c1 < nch;
  float vals[16];
  float lmax = -3.0e38f;
  if (a0) {
    u16x8 u = prow[c0];
#pragma unroll
    for (int e = 0; e < 8; ++e) {
      float f = (c0 * 8 + e <= row) ? bf2f(u[e]) : -3.0e38f;
      vals[e] = f; lmax = fmaxf(lmax, f);
    }
  } else {
#pragma unroll
    for (int e = 0; e < 8; ++e) vals[e] = -3.0e38f;
  }
  if (a1) {
    u16x8 u = prow[c1];
#pragma unroll
    for (int e = 0; e < 8; ++e) {
      float f = (c1 * 8 + e <= row) ? bf2f(u[e]) : -3.0e38f;
      vals[8 + e] = f; lmax = fmaxf(lmax, f);
    }
  } else {
#pragma unroll
    for (int e = 0; e < 8; ++e) vals[8 + e] = -3.0e38f;
  }
  __shared__ float red[8];
#pragma unroll
  for (int off = 32; off > 0; off >>= 1) lmax = fmaxf(lmax, __shfl_down(lmax, off, 64));
  if (lane == 0) red[wv] = lmax;
  __syncthreads();
  float m2 = fmaxf(fmaxf(red[0], red[1]), fmaxf(red[2], red[3]));
  float lsum = 0.f;
#pragma unroll
  for (int e = 0; e < 16; ++e) {
    float ev = __expf(vals[e] - m2);
    vals[e] = ev;
    lsum += ev;
  }
#pragma unroll
  for (int off = 32; off > 0; off >>= 1) lsum += __shfl_down(lsum, off, 64);
  if (lane == 0) red[4 + wv] = lsum;
  __syncthreads();
  float inv = 1.0f / (red[4] + red[5] + red[6] + red[7]);
  if (a0) {
    u16x8 u;
#pragma unroll
    for (int e = 0; e < 8; ++e) u[e] = f2bf(vals[e] * inv);
    prow[c0] = u;
  }
  if (a1) {
    u16x8 u;
#pragma unroll
    for (int e = 0; e < 8; ++e) u[e] = f2bf(vals[8 + e] * inv);
    prow[c1] = u;
  }
  u16x8 zz = (u16x8)(u16)0;
  for (int c = nch + tid; c < fend; c += 256) prow[c] = zz;
}

// ---------------------------------------------------------------------------
// gemm256q: 256x256-tile GEMM, BK=64. C = A[M,1024] @ Bt[N,1024]^T
// 8 waves (2M x 4N), per-wave 128x64 out. Ring-2 dbuf [2][256][64] per matrix
// (128 KiB). Per K-tile: {stage t+1 (8 gloads) | vmcnt(8) | SBAR | 64 MFMA
// with 8/4/8/4 interleaved ds_reads | SBAR}. LDS[r][c8] = G[r][c8^(r&7)].
// MODE 0: q/k/v proj (3 slots, z=slot)  MODE 1: causal scores (3|2 slots)
// MODE 3: out-projection (1 slot)
// ---------------------------------------------------------------------------
template <int MODE, bool OUT_BF16, bool HAS_BIAS>
__global__ __launch_bounds__(512, 2) void gemm256q(GemmPtrs p, int N, float cscale) {
  __shared__ __align__(16) u16 As[2][16384];   // [2][256 rows][64 k]
  __shared__ __align__(16) u16 Bs[2][16384];
  const int b = blockIdx.x;
  const int tid = threadIdx.x, lane = tid & 63, wv = tid >> 6;
  const int wm = (wv >> 2) << 7, wn = (wv & 3) << 6;
  const int lrow = lane & 15, lquad = lane >> 4;
  const int xsw = lrow & 7;
  const int ch0 = (lquad ^ xsw) << 3;          // k-chunk for ks=0 (elems)
  const int ch1 = ((4 + lquad) ^ xsw) << 3;    // ks=1
  const int arow = (wm + lrow) * 64;
  const int brow = (wn + lrow) * 64;
  // stage: thread t loads 16B at G[row=(t>>3)+64L][chunk=(t&7)^((t>>3)&7)],
  // dest linear -> LDS[r][c] = G[r][c^(r&7)]
  const int soff = (tid >> 3) * 1024 + (((tid & 7) ^ ((tid >> 3) & 7)) << 3);
  const int x = b & 7, u = b >> 3;            // XCD, index-on-XCD
  const int nslot = (MODE == 1) ? (u < 4 ? 3 : 2) : (MODE == 0 ? 3 : 1);

  struct TP { const u16* A; const u16* B; int tm, tn, z; };
  auto tileOf = [&](int s) {
    TP t;
    if (MODE == 0) {
      int i = x * 32 + u;                 // 8-row band per XCD, reused over 3 mats
      t.z = s; t.tm = (i >> 2) << 8; t.tn = (i & 3) << 8;
    } else if (MODE == 1) {
      int g = x * 68 + s * 32 + u;        // per-XCD contiguous tri range
      t.z = g / 136; int L = g - t.z * 136;
      int i = (int)((__fsqrt_rn(8.f * (float)L + 1.f) - 1.f) * 0.5f);
      while ((i + 1) * (i + 2) / 2 <= L) ++i;
      while (i * (i + 1) / 2 > L) --i;
      t.tm = i << 8; t.tn = (L - ((i * (i + 1)) >> 1)) << 8;
    } else {
      int i = x * 32 + u;
      t.z = 0; t.tm = (i >> 2) << 8; t.tn = (i & 3) << 8;
    }
    t.A = p.A[t.z] + (size_t)t.tm * 1024;
    t.B = p.B[t.z] + (size_t)t.tn * 1024;
    return t;
  };

  // staging cursor (1 K-tile ahead of compute)
  const u16* gA; const u16* gB; int stk = 0, sslot = 0;
  {
    TP t0 = tileOf(0);
    gA = t0.A + soff; gB = t0.B + soff;
  }
  auto adv = [&]() {
    gA += 64; gB += 64;
    if (++stk == 16) {
      stk = 0;
      if (++sslot < nslot) {
        TP t = tileOf(sslot);
        gA = t.A + soff; gB = t.B + soff;
      }
    }
  };
  auto stage = [&](int sb) __attribute__((always_inline)) {
#pragma unroll
    for (int L = 0; L < 4; ++L)
      __builtin_amdgcn_global_load_lds((as1cp)(gA + L * 65536),
                                       (as3p)(As[sb] + (tid + L * 512) * 8), 16, 0, 0);
#pragma unroll
    for (int L = 0; L < 4; ++L)
      __builtin_amdgcn_global_load_lds((as1cp)(gB + L * 65536),
                                       (as3p)(Bs[sb] + (tid + L * 512) * 8), 16, 0, 0);
    adv();
  };

  f32x4 acc[8][4];
#pragma unroll
  for (int i = 0; i < 8; ++i)
#pragma unroll
    for (int j = 0; j < 4; ++j) acc[i][j] = (f32x4){0.f, 0.f, 0.f, 0.f};

  auto epi = [&](int cs2) {
    TP t = tileOf(cs2);
    float bvv[4] = {0.f, 0.f, 0.f, 0.f};
    if constexpr (HAS_BIAS) {
#pragma unroll
      for (int n = 0; n < 4; ++n) bvv[n] = p.bias[t.z][t.tn + wn + n * 16 + lrow];
    }
#pragma unroll
    for (int m = 0; m < 8; ++m)
#pragma unroll
      for (int r = 0; r < 4; ++r) {
        size_t row = (size_t)(t.tm + wm + m * 16 + lquad * 4 + r);
#pragma unroll
        for (int n = 0; n < 4; ++n) {
          int col = t.tn + wn + n * 16 + lrow;
          float vvv = acc[m][n][r] * cscale + bvv[n];
          if (OUT_BF16) ((u16*)p.C[t.z])[row * N + col] = f2bf(vvv);
          else          ((float*)p.C[t.z])[row * N + col] = vvv;
        }
      }
#pragma unroll
    for (int m2 = 0; m2 < 8; ++m2)
#pragma unroll
      for (int n2 = 0; n2 < 4; ++n2) acc[m2][n2] = (f32x4){0.f, 0.f, 0.f, 0.f};
  };

  // prologue: stage tile 0 -> buf 0, publish
  stage(0);
  asm volatile("s_waitcnt vmcnt(0)");
  SBAR();
  SPIN();

  const int T = nslot * 16;
  int cs = 0;
  for (int t = 0; t < T; ++t) {
    const int cb = t & 1;
    if (t + 1 < T) {
      stage(cb ^ 1);                       // tile t+1 -> other buffer
      SPIN();
      asm volatile("s_waitcnt vmcnt(8)");  // tile t's 8 loads landed
    } else {
      SPIN();
      asm volatile("s_waitcnt vmcnt(0)");
    }
    SBAR();
    SPIN();
    __builtin_amdgcn_s_setprio(1);
    {
      bf16x8 af[4], bf[4];
      // (h0,k0): 8 reads, 16 MFMA
#pragma unroll
      for (int m = 0; m < 4; ++m) af[m] = *(const bf16x8*)&As[cb][arow + m * 1024 + ch0];
#pragma unroll
      for (int n = 0; n < 4; ++n) bf[n] = *(const bf16x8*)&Bs[cb][brow + n * 1024 + ch0];
#pragma unroll
      for (int m = 0; m < 4; ++m)
#pragma unroll
        for (int n = 0; n < 4; ++n)
          acc[m][n] = __builtin_amdgcn_mfma_f32_16x16x32_bf16(af[m], bf[n], acc[m][n], 0, 0, 0);
      // (h1,k0): 4 reads (B held), 16 MFMA
#pragma unroll
      for (int m = 0; m < 4; ++m) af[m] = *(const bf16x8*)&As[cb][arow + 4096 + m * 1024 + ch0];
#pragma unroll
      for (int m = 0; m < 4; ++m)
#pragma unroll
        for (int n = 0; n < 4; ++n)
          acc[4 + m][n] = __builtin_amdgcn_mfma_f32_16x16x32_bf16(af[m], bf[n], acc[4 + m][n], 0, 0, 0);
      // (h1,k1): 8 reads, 16 MFMA
#pragma unroll
      for (int m = 0; m < 4; ++m) af[m] = *(const bf16x8*)&As[cb][arow + 4096 + m * 1024 + ch1];
#pragma unroll
      for (int n = 0; n < 4; ++n) bf[n] = *(const bf16x8*)&Bs[cb][brow + n * 1024 + ch1];
#pragma unroll
      for (int m = 0; m < 4; ++m)
#pragma unroll
        for (int n = 0; n < 4; ++n)
          acc[4 + m][n] = __builtin_amdgcn_mfma_f32_16x16x32_bf16(af[m], bf[n], acc[4 + m][n], 0, 0, 0);
      // (h0,k1): 4 reads (B held), 16 MFMA
#pragma unroll
      for (int m = 0; m < 4; ++m) af[m] = *(const bf16x8*)&As[cb][arow + m * 1024 + ch1];
#pragma unroll
      for (int m = 0; m < 4; ++m)
#pragma unroll
        for (int n = 0; n < 4; ++n)
          acc[m][n] = __builtin_amdgcn_mfma_f32_16x16x32_bf16(af[m], bf[n], acc[m][n], 0, 0, 0);
    }
    __builtin_amdgcn_s_setprio(0);
    SBAR();                                // reads of buf cb done before reuse
    SPIN();
    if (((t + 1) & 15) == 0) { epi(cs); ++cs; }
  }
}

// ---------------------------------------------------------------------------
// gemm_pv64: ctx[tile 128x256] = attn[128,K] @ vT[256,K]^T, K=128(i+1) causal.
// BK=64. Pair (j, 31-j): every block exactly 66 K-tiles. Ring-2 dbuf, 96 KiB.
// Per K-tile: {stage t+1 (6 gloads) | vmcnt(6) | SBAR | 32 MFMA + 16 reads |
// SBAR}. 32 MFMA per barrier-pair (2x the old gemm_pv).
// ---------------------------------------------------------------------------
__global__ __launch_bounds__(512, 2) void gemm_pv64(GemmPtrs p) {
  __shared__ __align__(16) u16 As[2][8192];    // [2][128][64]
  __shared__ __align__(16) u16 Bs[2][16384];   // [2][256][64]
  const int b = blockIdx.x;
  const int tid = threadIdx.x, lane = tid & 63, wv = tid >> 6;
  const int wm = (wv >> 2) << 6, wn = (wv & 3) << 6;
  const int lrow = lane & 15, lquad = lane >> 4;
  const int xsw = lrow & 7;
  const int ch0 = (lquad ^ xsw) << 3;
  const int ch1 = ((4 + lquad) ^ xsw) << 3;
  const int arow = (wm + lrow) * 64;
  const int brow = (wn + lrow) * 64;
  const int soff = (tid >> 3) * 4096 + (((tid & 7) ^ ((tid >> 3) & 7)) << 3);
  const int x = b & 7, u = b >> 3;
  const int P = x * 32 + u;                   // n fastest within XCD (A reuse x4)
  const int z = P >> 6, j = (P >> 2) & 15, n4 = P & 3;
  const int i1 = j, i2 = 31 - j;
  const int tn = n4 << 8;
  const int T1 = 2 * (i1 + 1);
  const int T = 66;
  const u16* Abase = p.A[z];
  const u16* Bbase = p.B[z] + (size_t)tn * 4096;

  const u16* gA = Abase + (size_t)(i1 << 7) * 4096 + soff;
  const u16* gB = Bbase + soff;
  int stk = 0;
  auto adv = [&]() {
    gA += 64; gB += 64;
    if (++stk == T1) {
      gA = Abase + (size_t)(i2 << 7) * 4096 + soff;
      gB = Bbase + soff;
    }
  };
  auto stage = [&](int sb) __attribute__((always_inline)) {
#pragma unroll
    for (int L = 0; L < 2; ++L)
      __builtin_amdgcn_global_load_lds((as1cp)(gA + (size_t)L * 262144),
                                       (as3p)(As[sb] + (tid + L * 512) * 8), 16, 0, 0);
#pragma unroll
    for (int L = 0; L < 4; ++L)
      __builtin_amdgcn_global_load_lds((as1cp)(gB + (size_t)L * 262144),
                                       (as3p)(Bs[sb] + (tid + L * 512) * 8), 16, 0, 0);
    adv();
  };

  f32x4 acc[4][4];
#pragma unroll
  for (int i = 0; i < 4; ++i)
#pragma unroll
    for (int jj = 0; jj < 4; ++jj) acc[i][jj] = (f32x4){0.f, 0.f, 0.f, 0.f};

  auto epi = [&](int s) {
    int tm = (s ? i2 : i1) << 7;
#pragma unroll
    for (int m = 0; m < 4; ++m)
#pragma unroll
      for (int r = 0; r < 4; ++r) {
        size_t row = (size_t)(tm + wm + m * 16 + lquad * 4 + r);
#pragma unroll
        for (int n = 0; n < 4; ++n) {
          int col = tn + wn + n * 16 + lrow;
          ((u16*)p.C[z])[row * 1024 + col] = f2bf(acc[m][n][r]);
        }
      }
#pragma unroll
    for (int m2 = 0; m2 < 4; ++m2)
#pragma unroll
      for (int n2 = 0; n2 < 4; ++n2) acc[m2][n2] = (f32x4){0.f, 0.f, 0.f, 0.f};
  };

  // prologue
  stage(0);
  asm volatile("s_waitcnt vmcnt(0)");
  SBAR();
  SPIN();

  for (int t = 0; t < T; ++t) {
    const int cb = t & 1;
    if (t + 1 < T) {
      stage(cb ^ 1);
      SPIN();
      asm volatile("s_waitcnt vmcnt(6)");
    } else {
      SPIN();
      asm volatile("s_waitcnt vmcnt(0)");
    }
    SBAR();
    SPIN();
    __builtin_amdgcn_s_setprio(1);
    {
      bf16x8 af[4], bf[4];
#pragma unroll
      for (int m = 0; m < 4; ++m) af[m] = *(const bf16x8*)&As[cb][arow + m * 1024 + ch0];
#pragma unroll
      for (int n = 0; n < 4; ++n) bf[n] = *(const bf16x8*)&Bs[cb][brow + n * 1024 + ch0];
#pragma unroll
      for (int m = 0; m < 4; ++m)
#pragma unroll
        for (int n = 0; n < 4; ++n)
          acc[m][n] = __builtin_amdgcn_mfma_f32_16x16x32_bf16(af[m], bf[n], acc[m][n], 0, 0, 0);
#pragma unroll
      for (int m = 0; m < 4; ++m) af[m] = *(const bf16x8*)&As[cb][arow + m * 1024 + ch1];
#pragma unroll
      for (int n = 0; n < 4; ++n) bf[n] = *(const bf16x8*)&Bs[cb][brow + n * 1024 + ch1];
#pragma unroll
      for (int m = 0; m < 4; ++m)
#pragma unroll
        for (int n = 0; n < 4; ++n)
          acc[m][n] = __builtin_amdgcn_mfma_f32_16x16x32_bf16(af[m], bf[n], acc[m][n], 0, 0, 0);
    }
    __builtin_amdgcn_s_setprio(0);
    SBAR();
    SPIN();
    if (t + 1 == T1) epi(0);
  }
  epi(1);
}

// ---------------------------------------------------------------------------
extern "C" void kernel_launch(void* const* d_in, const int* in_sizes, int n_in,
                              void* d_out, int out_size, void* d_ws, size_t ws_size,
                              hipStream_t stream) {
  const float* x  = (const float*)d_in[0];
  const float* Wq = (const float*)d_in[1];
  const float* bq = (const float*)d_in[2];
  const float* Wk = (const float*)d_in[3];
  const float* bk = (const float*)d_in[4];
  const float* Wv = (const float*)d_in[5];
  const float* bv = (const float*)d_in[6];
  const float* Wo = (const float*)d_in[7];
  const float* bo = (const float*)d_in[8];

  const int S = 4096, D = 1024;
  const size_t XE = (size_t)4 * S * D;
  const size_t BSE = (size_t)S * D;

  char* ws = (char*)d_ws;
  u16* xb  = (u16*)(ws + 0);                     // [16384,1024]; dead after proj -> vT
  u16* q   = (u16*)(ws + 33554432);
  u16* k   = (u16*)(ws + 67108864);
  u16* v   = (u16*)(ws + 100663296);             // dead after transpose -> attn3
  u16* ctx = (u16*)(ws + 134217728);
  u16* wqT = (u16*)(ws + 167772160);
  u16* wkT = wqT + 1048576;
  u16* wvT = wkT + 1048576;
  u16* woT = wvT + 1048576;
  u16* attn2 = (u16*)(ws + 176160768);           // [4096,4096] bf16
  u16* attn0 = (u16*)d_out;                      // d_out 67MB, dead until out-proj
  u16* attn1 = attn0 + (size_t)S * S;
  u16* attn3 = v;
  u16* vT = xb;                                  // [1024,4096] per batch, contiguous
  u16* attn[4] = {attn0, attn1, attn2, attn3};

  // 1. cast x -> bf16
  cast_f32_bf16<<<(int)(XE / 4 / 256), 256, 0, stream>>>(x, xb, (int)(XE / 4));
  // 2. weight transposes
  {
    TransPtrs tp = {{Wq, Wk, Wv, Wo}, {wqT, wkT, wvT, woT}};
    transpose_to_bf16<true><<<dim3(32, 32, 4), dim3(32, 8), 0, stream>>>(tp, D, D);
  }
  // 3. q/k/v projections: 768 tiles = 256 blocks x 3 slots (z = slot)
  {
    GemmPtrs gp = {{xb, xb, xb, xb}, {wqT, wkT, wvT, wqT},
                   {bq, bk, bv, bq}, {q, k, v, q}};
    gemm256q<0, true, true><<<256, 512, 0, stream>>>(gp, D, 1.0f);
  }
  // 4. v -> v^T per batch (overwrites dead xb)
  {
    TransPtrs tp = {{v, v + BSE, v + 2 * BSE, v + 3 * BSE},
                    {vT, vT + BSE, vT + 2 * BSE, vT + 3 * BSE}};
    transpose_to_bf16<false><<<dim3(D / 32, S / 32, 4), dim3(32, 8), 0, stream>>>(tp, S, D);
  }
  // 5. scores = (q k^T)*scale: 544 tri tiles, per-XCD contiguous 68-ranges
  {
    GemmPtrs gp = {{q, q + BSE, q + 2 * BSE, q + 3 * BSE},
                   {k, k + BSE, k + 2 * BSE, k + 3 * BSE},
                   {nullptr, nullptr, nullptr, nullptr},
                   {attn[0], attn[1], attn[2], attn[3]}};
    gemm256q<1, true, false><<<256, 512, 0, stream>>>(gp, S, 0.03125f);
  }
  // 6. causal softmax in-place (trimmed + fringe zeros)
  {
    SmPtrs sp = {{attn[0], attn[1], attn[2], attn[3]}};
    softmax_causal<<<dim3(S, 4), 256, 0, stream>>>(sp);
  }
  // 7. ctx = attn @ v: paired causal tiles, 256 blocks x 66 K-tiles (balanced)
  {
    GemmPtrs gp = {{attn[0], attn[1], attn[2], attn[3]},
                   {vT, vT + BSE, vT + 2 * BSE, vT + 3 * BSE},
                   {nullptr, nullptr, nullptr, nullptr},
                   {ctx, ctx + BSE, ctx + 2 * BSE, ctx + 3 * BSE}};
    gemm_pv64<<<256, 512, 0, stream>>>(gp);
  }
  // 8. out = ctx Wo^T + bo (fp32 -> d_out)
  {
    GemmPtrs gp = {{ctx, ctx, ctx, ctx}, {woT, woT, woT, woT},
                   {bo, bo, bo, bo}, {d_out, d_out, d_out, d_out}};
    gemm256q<3, false, true><<<256, 512, 0, stream>>>(gp, D, 1.0f);
  }
}

// Round 6
// 508.268 us; speedup vs baseline: 1.0206x; 1.0206x over previous
//
#include <hip/hip_runtime.h>

// ---------------------------------------------------------------------------
// StandAttention: out = softmax_causal((xWq+bq)(xWk+bk)^T / sqrt(d)) (xWv+bv) Wo + bo
// b=4, s=4096, d=1024. fp32 in/out, bf16 MFMA compute.
//
// R12 changes vs R11 (R11: 518us, BK=64 regressed to 31%. Accounting across
// all 6 variants: MFMA (1241cy) + LDS reads (~1150cy) SUM per K-tile; never
// overlap. Only cross-WAVE overlap is possible: m201's phase form
// {reads | stage | SBAR | per-wave lgkmcnt(0) | MFMA-only} lets the first
// wave whose reads land start MFMA while the LDS port drains other waves'
// reads. All my variants consumed reads issued a phase earlier -> strict
// alternation. Port the verified structure):
//  - gemm8ph: BK=32, ring-3 (96KB), 2 phases/K-tile, each {read frags for
//    THIS phase | stage half of t+2 | SBAR | lgkm(0)+schedbar | 16 MFMA |
//    SBAR}; vmcnt(4) once per K-tile (dist-2 prefetch).
//  - gemm_pv3: same form, 1 phase/K-tile, ring-3 (72KB), vmcnt(3).
//  - Zero-conflict swizzle + XCD tile maps from R8 kept (both proven).
// ---------------------------------------------------------------------------

typedef unsigned short u16;
typedef __attribute__((ext_vector_type(4))) unsigned short u16x4;
typedef __attribute__((ext_vector_type(8))) unsigned short u16x8;
typedef __attribute__((ext_vector_type(8))) __bf16 bf16x8;
typedef __attribute__((ext_vector_type(4))) float f32x4;

typedef const __attribute__((address_space(1))) void* as1cp;
typedef __attribute__((address_space(3))) void* as3p;

#define SBAR() __builtin_amdgcn_s_barrier()
#define SPIN() __builtin_amdgcn_sched_barrier(0)

struct GemmPtrs {
  const u16* A[4];
  const u16* B[4];
  const float* bias[4];
  void* C[4];
};
struct TransPtrs {
  const void* in[4];
  u16* out[4];
};
struct SmPtrs {
  u16* P[4];
};

__device__ __forceinline__ u16 f2bf(float f) {
  union { float f; unsigned int i; } c; c.f = f;
  unsigned int r = c.i + 0x7fffu + ((c.i >> 16) & 1u);   // RNE
  return (u16)(r >> 16);
}
__device__ __forceinline__ float bf2f(u16 u) {
  union { unsigned int i; float f; } c; c.i = ((unsigned int)u) << 16;
  return c.f;
}

// ---------------- cast fp32 -> bf16 (vectorized) ----------------
__global__ __launch_bounds__(256) void cast_f32_bf16(const float* __restrict__ in,
                                                     u16* __restrict__ out, int n4) {
  int i = blockIdx.x * blockDim.x + threadIdx.x;
  if (i >= n4) return;
  float4 v = ((const float4*)in)[i];
  u16x4 u;
  u.x = f2bf(v.x); u.y = f2bf(v.y); u.z = f2bf(v.z); u.w = f2bf(v.w);
  ((u16x4*)out)[i] = u;
}

// ---------------- LDS-tiled transpose (-> bf16), batched by z ----------------
template <bool IN_F32>
__global__ __launch_bounds__(256) void transpose_to_bf16(TransPtrs tp, int R, int C) {
  __shared__ u16 t[32][34];
  int z = blockIdx.z;
  int tx = threadIdx.x, ty = threadIdx.y;
  int c0 = blockIdx.x * 32, r0 = blockIdx.y * 32;
#pragma unroll
  for (int dy = 0; dy < 4; ++dy) {
    int r = r0 + ty + dy * 8;
    int c = c0 + tx;
    u16 hv;
    if (IN_F32) hv = f2bf(((const float*)tp.in[z])[(size_t)r * C + c]);
    else        hv = ((const u16*)tp.in[z])[(size_t)r * C + c];
    t[ty + dy * 8][tx] = hv;
  }
  __syncthreads();
  u16* op = tp.out[z];
#pragma unroll
  for (int dy = 0; dy < 4; ++dy) {
    int a = ty + dy * 8;
    op[(size_t)(c0 + a) * R + r0 + tx] = t[tx][a];
  }
}

// ---------------- causal softmax, in-place, trimmed to j<=row ----------------
__global__ __launch_bounds__(256) void softmax_causal(SmPtrs sp) {
  int row = blockIdx.x;
  u16* P = sp.P[blockIdx.y];
  int tid = threadIdx.x;
  int lane = tid & 63, wv = tid >> 6;
  u16x8* prow = (u16x8*)(P + (size_t)row * 4096);
  int nch = (row >> 3) + 1;           // vec8 chunks containing any j<=row
  int fend = ((row >> 7) + 1) << 4;   // chunks to the 128 boundary PV reads
  int c0 = tid, c1 = tid + 256;
  bool a0 = c0 < nch, a1 = c1 < nch;
  float vals[16];
  float lmax = -3.0e38f;
  if (a0) {
    u16x8 u = prow[c0];
#pragma unroll
    for (int e = 0; e < 8; ++e) {
      float f = (c0 * 8 + e <= row) ? bf2f(u[e]) : -3.0e38f;
      vals[e] = f; lmax = fmaxf(lmax, f);
    }
  } else {
#pragma unroll
    for (int e = 0; e < 8; ++e) vals[e] = -3.0e38f;
  }
  if (a1) {
    u16x8 u = prow[c1];
#pragma unroll
    for (int e = 0; e < 8; ++e) {
      float f = (c1 * 8 + e <= row) ? bf2f(u[e]) : -3.0e38f;
      vals[8 + e] = f; lmax = fmaxf(lmax, f);
    }
  } else {
#pragma unroll
    for (int e = 0; e < 8; ++e) vals[8 + e] = -3.0e38f;
  }
  __shared__ float red[8];
#pragma unroll
  for (int off = 32; off > 0; off >>= 1) lmax = fmaxf(lmax, __shfl_down(lmax, off, 64));
  if (lane == 0) red[wv] = lmax;
  __syncthreads();
  float m2 = fmaxf(fmaxf(red[0], red[1]), fmaxf(red[2], red[3]));
  float lsum = 0.f;
#pragma unroll
  for (int e = 0; e < 16; ++e) {
    float ev = __expf(vals[e] - m2);
    vals[e] = ev;
    lsum += ev;
  }
#pragma unroll
  for (int off = 32; off > 0; off >>= 1) lsum += __shfl_down(lsum, off, 64);
  if (lane == 0) red[4 + wv] = lsum;
  __syncthreads();
  float inv = 1.0f / (red[4] + red[5] + red[6] + red[7]);
  if (a0) {
    u16x8 u;
#pragma unroll
    for (int e = 0; e < 8; ++e) u[e] = f2bf(vals[e] * inv);
    prow[c0] = u;
  }
  if (a1) {
    u16x8 u;
#pragma unroll
    for (int e = 0; e < 8; ++e) u[e] = f2bf(vals[8 + e] * inv);
    prow[c1] = u;
  }
  u16x8 zz = (u16x8)(u16)0;
  for (int c = nch + tid; c < fend; c += 256) prow[c] = zz;
}

// ---------------------------------------------------------------------------
// gemm8ph: 256x256 tile, BK=32, 8 waves (2M x 4N), per-wave 128x64 out.
// Ring-3 LDS (96KB). Per K-tile t (buf c=t%3, stage s=(t+2)%3):
//  ph0: {read A m0-3 + B n0-3 | stage A(t+2) | SBAR | lgkm(0) | 16 MFMA | SBAR}
//  ph1: {read A m4-7          | stage B(t+2) | vmcnt(4) | SBAR | lgkm(0) |
//        16 MFMA | SBAR}
// MODE 0: q/k/v proj (3 slots, z=slot)  MODE 1: causal scores (3|2 slots)
// MODE 3: out-projection (1 slot)
// ---------------------------------------------------------------------------
template <int MODE, bool OUT_BF16, bool HAS_BIAS>
__global__ __launch_bounds__(512, 2) void gemm8ph(GemmPtrs p, int N, float cscale) {
  __shared__ __align__(16) u16 As[3][8192];   // ring x 256 rows x 32 k
  __shared__ __align__(16) u16 Bs[3][8192];
  const int b = blockIdx.x;
  const int tid = threadIdx.x, lane = tid & 63, wv = tid >> 6;
  const int wm = (wv >> 2) << 7, wn = (wv & 3) << 6;
  const int lrow = lane & 15, lquad = lane >> 4;
  const int xs = (lquad ^ ((lrow >> 1) & 3)) << 3;
  const int aoff0 = (wm + lrow) * 32 + xs;
  const int boff0 = (wn + lrow) * 32 + xs;
  // stage src pre-swizzle: LDS[r][c] = G[r][c ^ ((r>>1)&3)]  (R8-proven, 0 conflicts)
  const int soff = (tid >> 2) * 1024 + (((tid & 3) ^ ((tid >> 3) & 3)) << 3);
  const int x = b & 7, u = b >> 3;            // XCD, index-on-XCD
  const int nslot = (MODE == 1) ? (u < 4 ? 3 : 2) : (MODE == 0 ? 3 : 1);

  struct TP { const u16* A; const u16* B; int tm, tn, z; };
  auto tileOf = [&](int s) {
    TP t;
    if (MODE == 0) {
      int i = x * 32 + u;                 // 8-row band per XCD, reused over 3 mats
      t.z = s; t.tm = (i >> 2) << 8; t.tn = (i & 3) << 8;
    } else if (MODE == 1) {
      int g = x * 68 + s * 32 + u;        // per-XCD contiguous tri range
      t.z = g / 136; int L = g - t.z * 136;
      int i = (int)((__fsqrt_rn(8.f * (float)L + 1.f) - 1.f) * 0.5f);
      while ((i + 1) * (i + 2) / 2 <= L) ++i;
      while (i * (i + 1) / 2 > L) --i;
      t.tm = i << 8; t.tn = (L - ((i * (i + 1)) >> 1)) << 8;
    } else {
      int i = x * 32 + u;
      t.z = 0; t.tm = (i >> 2) << 8; t.tn = (i & 3) << 8;
    }
    t.A = p.A[t.z] + (size_t)t.tm * 1024;
    t.B = p.B[t.z] + (size_t)t.tn * 1024;
    return t;
  };

  // staging cursor (2 K-tiles ahead of compute)
  const u16* gA; const u16* gB; int stk = 0, sslot = 0;
  {
    TP t0 = tileOf(0);
    gA = t0.A + soff; gB = t0.B + soff;
  }
  auto adv = [&]() {
    gA += 32; gB += 32;
    if (++stk == 32) {
      stk = 0;
      if (++sslot < nslot) {
        TP t = tileOf(sslot);
        gA = t.A + soff; gB = t.B + soff;
      }
    }
  };
  auto stgA = [&](int s) __attribute__((always_inline)) {
    __builtin_amdgcn_global_load_lds((as1cp)gA, (as3p)(As[s] + wv * 512), 16, 0, 0);
    __builtin_amdgcn_global_load_lds((as1cp)(gA + 131072), (as3p)(As[s] + 4096 + wv * 512), 16, 0, 0);
  };
  auto stgB = [&](int s) __attribute__((always_inline)) {
    __builtin_amdgcn_global_load_lds((as1cp)gB, (as3p)(Bs[s] + wv * 512), 16, 0, 0);
    __builtin_amdgcn_global_load_lds((as1cp)(gB + 131072), (as3p)(Bs[s] + 4096 + wv * 512), 16, 0, 0);
    adv();
  };

  f32x4 acc[8][4];
#pragma unroll
  for (int i = 0; i < 8; ++i)
#pragma unroll
    for (int j = 0; j < 4; ++j) acc[i][j] = (f32x4){0.f, 0.f, 0.f, 0.f};

  auto epi = [&](int cs2) {
    TP t = tileOf(cs2);
    float bvv[4] = {0.f, 0.f, 0.f, 0.f};
    if constexpr (HAS_BIAS) {
#pragma unroll
      for (int n = 0; n < 4; ++n) bvv[n] = p.bias[t.z][t.tn + wn + n * 16 + lrow];
    }
#pragma unroll
    for (int m = 0; m < 8; ++m)
#pragma unroll
      for (int r = 0; r < 4; ++r) {
        size_t row = (size_t)(t.tm + wm + m * 16 + lquad * 4 + r);
#pragma unroll
        for (int n = 0; n < 4; ++n) {
          int col = t.tn + wn + n * 16 + lrow;
          float vvv = acc[m][n][r] * cscale + bvv[n];
          if (OUT_BF16) ((u16*)p.C[t.z])[row * N + col] = f2bf(vvv);
          else          ((float*)p.C[t.z])[row * N + col] = vvv;
        }
      }
#pragma unroll
    for (int m2 = 0; m2 < 8; ++m2)
#pragma unroll
      for (int n2 = 0; n2 < 4; ++n2) acc[m2][n2] = (f32x4){0.f, 0.f, 0.f, 0.f};
  };

  // prologue: stage tiles 0,1 -> slots 0,1; publish tile 0 (tile 1 in flight)
  stgA(0); stgB(0);
  stgA(1); stgB(1);
  asm volatile("s_waitcnt vmcnt(4)");
  SBAR();
  SPIN();

  const int T = nslot * 32;
  int cs = 0, c = 0;
  for (int t = 0; t < T; ++t) {
    const int s = (c >= 1) ? c - 1 : 2;       // (c+2)%3
    const bool stg = (t + 2) < T;
    bf16x8 af[4], bf[4];
    // ---------------- phase 0: m0-3 x n0-3 ----------------
#pragma unroll
    for (int m = 0; m < 4; ++m) af[m] = *(const bf16x8*)&As[c][aoff0 + m * 512];
#pragma unroll
    for (int n = 0; n < 4; ++n) bf[n] = *(const bf16x8*)&Bs[c][boff0 + n * 512];
    if (stg) stgA(s);
    SPIN();
    SBAR();
    asm volatile("s_waitcnt lgkmcnt(0)");
    SPIN();
    __builtin_amdgcn_s_setprio(1);
#pragma unroll
    for (int m = 0; m < 4; ++m)
#pragma unroll
      for (int n = 0; n < 4; ++n)
        acc[m][n] = __builtin_amdgcn_mfma_f32_16x16x32_bf16(af[m], bf[n], acc[m][n], 0, 0, 0);
    __builtin_amdgcn_s_setprio(0);
    SPIN();
    SBAR();
    // ---------------- phase 1: m4-7 x n0-3 (B held) ----------------
#pragma unroll
    for (int m = 0; m < 4; ++m) af[m] = *(const bf16x8*)&As[c][aoff0 + 2048 + m * 512];
    if (stg) stgB(s);
    SPIN();
    if (stg)               asm volatile("s_waitcnt vmcnt(4)");
    else if (t + 1 < T)    asm volatile("s_waitcnt vmcnt(0)");
    SBAR();
    asm volatile("s_waitcnt lgkmcnt(0)");
    SPIN();
    __builtin_amdgcn_s_setprio(1);
#pragma unroll
    for (int m = 0; m < 4; ++m)
#pragma unroll
      for (int n = 0; n < 4; ++n)
        acc[4 + m][n] = __builtin_amdgcn_mfma_f32_16x16x32_bf16(af[m], bf[n], acc[4 + m][n], 0, 0, 0);
    __builtin_amdgcn_s_setprio(0);
    SPIN();
    SBAR();
    if (((t + 1) & 31) == 0) { SPIN(); epi(cs); ++cs; }
    if (++c == 3) c = 0;
  }
}

// ---------------------------------------------------------------------------
// gemm_pv3: ctx[tile 128x256] = attn[128,K] @ vT[256,K]^T, K=128(i+1) causal.
// BK=32. Pair (i,31-i): every block exactly 132 K-tiles. Ring-3 (72KB).
// Per K-tile: {read A m0-3 + B n0-3 | stage t+2 (3 gloads) | vmcnt(3) | SBAR |
// lgkm(0) | 16 MFMA | SBAR}.
// ---------------------------------------------------------------------------
__global__ __launch_bounds__(512, 2) void gemm_pv3(GemmPtrs p) {
  __shared__ __align__(16) u16 As[3][4096];   // 128 x 32
  __shared__ __align__(16) u16 Bs[3][8192];   // 256 x 32
  const int b = blockIdx.x;
  const int tid = threadIdx.x, lane = tid & 63, wv = tid >> 6;
  const int wm = (wv >> 2) << 6, wn = (wv & 3) << 6;
  const int lrow = lane & 15, lquad = lane >> 4;
  const int xs = (lquad ^ ((lrow >> 1) & 3)) << 3;
  const int aoff0 = (wm + lrow) * 32 + xs;
  const int boff0 = (wn + lrow) * 32 + xs;
  const int soff = (tid >> 2) * 4096 + (((tid & 3) ^ ((tid >> 3) & 3)) << 3);
  const int x = b & 7, u = b >> 3;
  const int P = x * 32 + u;                   // n fastest within XCD (A reuse x4)
  const int z = P >> 6, j = (P >> 2) & 15, n4 = P & 3;
  const int i1 = j, i2 = 31 - j;
  const int tn = n4 << 8;
  const int T1 = (i1 + 1) * 4;
  const int niter1 = (i2 + 1) * 4;
  const u16* Abase = p.A[z];
  const u16* Bbase = p.B[z] + (size_t)tn * 4096;

  const u16* gA = Abase + (size_t)(i1 << 7) * 4096 + soff;
  const u16* gB = Bbase + soff;
  int stk = 0, sslot = 0;
  auto adv = [&]() {
    gA += 32; gB += 32;
    ++stk;
    if (sslot == 0 && stk == T1) {
      stk = 0; sslot = 1;
      gA = Abase + (size_t)(i2 << 7) * 4096 + soff;
      gB = Bbase + soff;
    } else if (sslot == 1 && stk == niter1) {
      stk = 0; sslot = 2;
    }
  };
  auto stage = [&](int s) __attribute__((always_inline)) {
    __builtin_amdgcn_global_load_lds((as1cp)gA, (as3p)(As[s] + wv * 512), 16, 0, 0);
    __builtin_amdgcn_global_load_lds((as1cp)gB, (as3p)(Bs[s] + wv * 512), 16, 0, 0);
    __builtin_amdgcn_global_load_lds((as1cp)(gB + 524288), (as3p)(Bs[s] + 4096 + wv * 512), 16, 0, 0);
    adv();
  };

  f32x4 acc[4][4];
#pragma unroll
  for (int i = 0; i < 4; ++i)
#pragma unroll
    for (int jj = 0; jj < 4; ++jj) acc[i][jj] = (f32x4){0.f, 0.f, 0.f, 0.f};

  auto epi = [&](int s) {
    int tm = (s ? i2 : i1) << 7;
#pragma unroll
    for (int m = 0; m < 4; ++m)
#pragma unroll
      for (int r = 0; r < 4; ++r) {
        size_t row = (size_t)(tm + wm + m * 16 + lquad * 4 + r);
#pragma unroll
        for (int n = 0; n < 4; ++n) {
          int col = tn + wn + n * 16 + lrow;
          ((u16*)p.C[z])[row * 1024 + col] = f2bf(acc[m][n][r]);
        }
      }
#pragma unroll
    for (int m2 = 0; m2 < 4; ++m2)
#pragma unroll
      for (int n2 = 0; n2 < 4; ++n2) acc[m2][n2] = (f32x4){0.f, 0.f, 0.f, 0.f};
  };

  // prologue: stage tiles 0,1; publish tile 0 (tile 1's 3 in flight)
  stage(0); stage(1);
  asm volatile("s_waitcnt vmcnt(3)");
  SBAR();
  SPIN();

  const int T = 132;
  int c = 0;
  for (int t = 0; t < T; ++t) {
    const int s = (c >= 1) ? c - 1 : 2;       // (c+2)%3
    const bool stg = (t + 2) < T;
    bf16x8 af[4], bf[4];
#pragma unroll
    for (int m = 0; m < 4; ++m) af[m] = *(const bf16x8*)&As[c][aoff0 + m * 512];
#pragma unroll
    for (int n = 0; n < 4; ++n) bf[n] = *(const bf16x8*)&Bs[c][boff0 + n * 512];
    if (stg) stage(s);
    SPIN();
    if (stg)            asm volatile("s_waitcnt vmcnt(3)");
    else if (t + 1 < T) asm volatile("s_waitcnt vmcnt(0)");
    SBAR();
    asm volatile("s_waitcnt lgkmcnt(0)");
    SPIN();
    __builtin_amdgcn_s_setprio(1);
#pragma unroll
    for (int m = 0; m < 4; ++m)
#pragma unroll
      for (int n = 0; n < 4; ++n)
        acc[m][n] = __builtin_amdgcn_mfma_f32_16x16x32_bf16(af[m], bf[n], acc[m][n], 0, 0, 0);
    __builtin_amdgcn_s_setprio(0);
    SPIN();
    SBAR();
    if (t + 1 == T1) { SPIN(); epi(0); }
    if (++c == 3) c = 0;
  }
  epi(1);
}

// ---------------------------------------------------------------------------
extern "C" void kernel_launch(void* const* d_in, const int* in_sizes, int n_in,
                              void* d_out, int out_size, void* d_ws, size_t ws_size,
                              hipStream_t stream) {
  const float* x  = (const float*)d_in[0];
  const float* Wq = (const float*)d_in[1];
  const float* bq = (const float*)d_in[2];
  const float* Wk = (const float*)d_in[3];
  const float* bk = (const float*)d_in[4];
  const float* Wv = (const float*)d_in[5];
  const float* bv = (const float*)d_in[6];
  const float* Wo = (const float*)d_in[7];
  const float* bo = (const float*)d_in[8];

  const int S = 4096, D = 1024;
  const size_t XE = (size_t)4 * S * D;
  const size_t BSE = (size_t)S * D;

  char* ws = (char*)d_ws;
  u16* xb  = (u16*)(ws + 0);                     // [16384,1024]; dead after proj -> vT
  u16* q   = (u16*)(ws + 33554432);
  u16* k   = (u16*)(ws + 67108864);
  u16* v   = (u16*)(ws + 100663296);             // dead after transpose -> attn3
  u16* ctx = (u16*)(ws + 134217728);
  u16* wqT = (u16*)(ws + 167772160);
  u16* wkT = wqT + 1048576;
  u16* wvT = wkT + 1048576;
  u16* woT = wvT + 1048576;
  u16* attn2 = (u16*)(ws + 176160768);           // [4096,4096] bf16
  u16* attn0 = (u16*)d_out;                      // d_out 67MB, dead until out-proj
  u16* attn1 = attn0 + (size_t)S * S;
  u16* attn3 = v;
  u16* vT = xb;                                  // [1024,4096] per batch, contiguous
  u16* attn[4] = {attn0, attn1, attn2, attn3};

  // 1. cast x -> bf16
  cast_f32_bf16<<<(int)(XE / 4 / 256), 256, 0, stream>>>(x, xb, (int)(XE / 4));
  // 2. weight transposes
  {
    TransPtrs tp = {{Wq, Wk, Wv, Wo}, {wqT, wkT, wvT, woT}};
    transpose_to_bf16<true><<<dim3(32, 32, 4), dim3(32, 8), 0, stream>>>(tp, D, D);
  }
  // 3. q/k/v projections: 768 tiles = 256 blocks x 3 slots (z = slot)
  {
    GemmPtrs gp = {{xb, xb, xb, xb}, {wqT, wkT, wvT, wqT},
                   {bq, bk, bv, bq}, {q, k, v, q}};
    gemm8ph<0, true, true><<<256, 512, 0, stream>>>(gp, D, 1.0f);
  }
  // 4. v -> v^T per batch (overwrites dead xb)
  {
    TransPtrs tp = {{v, v + BSE, v + 2 * BSE, v + 3 * BSE},
                    {vT, vT + BSE, vT + 2 * BSE, vT + 3 * BSE}};
    transpose_to_bf16<false><<<dim3(D / 32, S / 32, 4), dim3(32, 8), 0, stream>>>(tp, S, D);
  }
  // 5. scores = (q k^T)*scale: 544 tri tiles, per-XCD contiguous 68-ranges
  {
    GemmPtrs gp = {{q, q + BSE, q + 2 * BSE, q + 3 * BSE},
                   {k, k + BSE, k + 2 * BSE, k + 3 * BSE},
                   {nullptr, nullptr, nullptr, nullptr},
                   {attn[0], attn[1], attn[2], attn[3]}};
    gemm8ph<1, true, false><<<256, 512, 0, stream>>>(gp, S, 0.03125f);
  }
  // 6. causal softmax in-place (trimmed + fringe zeros)
  {
    SmPtrs sp = {{attn[0], attn[1], attn[2], attn[3]}};
    softmax_causal<<<dim3(S, 4), 256, 0, stream>>>(sp);
  }
  // 7. ctx = attn @ v: paired causal tiles, 256 blocks x 132 K-tiles (balanced)
  {
    GemmPtrs gp = {{attn[0], attn[1], attn[2], attn[3]},
                   {vT, vT + BSE, vT + 2 * BSE, vT + 3 * BSE},
                   {nullptr, nullptr, nullptr, nullptr},
                   {ctx, ctx + BSE, ctx + 2 * BSE, ctx + 3 * BSE}};
    gemm_pv3<<<256, 512, 0, stream>>>(gp);
  }
  // 8. out = ctx Wo^T + bo (fp32 -> d_out)
  {
    GemmPtrs gp = {{ctx, ctx, ctx, ctx}, {woT, woT, woT, woT},
                   {bo, bo, bo, bo}, {d_out, d_out, d_out, d_out}};
    gemm8ph<3, false, true><<<256, 512, 0, stream>>>(gp, D, 1.0f);
  }
}